// Round 4
// baseline (126.873 us; speedup 1.0000x reference)
//
#include <hip/hip_runtime.h>
#include <hip/hip_bf16.h>

// out = x @ (Wc + Wn) + b   -- gamma/segment ops in the reference are dead code.
// x: [100000,128] f32, Wc/Wn: [128,128] f32, b: [128] f32, out: [100000,128] f32.
//
// Single fused kernel:
//   * Each block builds Wt[n][k] = bf16(Wc[k][n]+Wn[k][n]) in LDS directly
//     (L2-resident 128KB read; no prep kernel, no graph dependency, no ws).
//   * All x fragments are loaded+converted BEFORE the staging barrier, so
//     global x latency overlaps W staging; the main loop is pure LDS+MFMA.
//   * MFMA operands: A = W^T fragment, B = x fragment (identical input lane
//     maps), so D[m=out_col][n=x_row] gives 4 contiguous out columns per
//     lane -> float4 nontemporal stores.

#define NROWS 100000

typedef __attribute__((ext_vector_type(8))) __bf16 bf16x8;
typedef __attribute__((ext_vector_type(4))) float f32x4;

__device__ __forceinline__ bf16x8 pack8(const float4 lo, const float4 hi) {
    bf16x8 r;  // gfx950: v_cvt_pk_bf16_f32 (RNE)
    r[0] = (__bf16)lo.x; r[1] = (__bf16)lo.y; r[2] = (__bf16)lo.z; r[3] = (__bf16)lo.w;
    r[4] = (__bf16)hi.x; r[5] = (__bf16)hi.y; r[6] = (__bf16)hi.z; r[7] = (__bf16)hi.w;
    return r;
}

// 128 rows per block, 4 waves x 32 rows, full N=128 / K=128 per block.
__global__ __launch_bounds__(256) void fout_fused(
    const float* __restrict__ x, const float* __restrict__ Wc,
    const float* __restrict__ Wn, const float* __restrict__ bias_g,
    float* __restrict__ out) {

    // 136-short row stride: rows 16B-aligned (272B) for ds_read_b128.
    __shared__ __align__(16) __bf16 sWt[128 * 136];

    const int tid  = threadIdx.x;
    const int wave = tid >> 6;
    const int lane = tid & 63;
    const int quad = lane >> 4;
    const int l16  = lane & 15;

    const long rowbase = (long)blockIdx.x * 128 + wave * 32;
    const bool valid = rowbase < NROWS;   // 100000 % 32 == 0: whole-wave granularity

    // ---- x prefetch: all fragments, converted to bf16 (32 VGPRs total) ----
    // B[k = quad*8 + j][n = lane&15] -> rows (rowbase+l16) and (+16)
    bf16x8 xb[2][4];
    if (valid) {
        const float* xr0 = x + (rowbase + l16) * 128;
        const float* xr1 = xr0 + 16 * 128;
        #pragma unroll
        for (int kc = 0; kc < 4; ++kc) {
            const int ko = kc * 32 + quad * 8;
            xb[0][kc] = pack8(*(const float4*)(xr0 + ko), *(const float4*)(xr0 + ko + 4));
            xb[1][kc] = pack8(*(const float4*)(xr1 + ko), *(const float4*)(xr1 + ko + 4));
        }
    }

    // ---- W staging: coalesced float4 reads of Wc/Wn, transpose into LDS ----
    // float4 chunk f in natural [k][n] order: k = f>>5, n4 = f&31.
    const float4* Wc4 = (const float4*)Wc;
    const float4* Wn4 = (const float4*)Wn;
    #pragma unroll 4
    for (int it = 0; it < 16; ++it) {
        const int f = it * 256 + tid;
        const int k = f >> 5, n4 = f & 31;
        float4 a = Wc4[f], b = Wn4[f];
        sWt[(n4 * 4 + 0) * 136 + k] = (__bf16)(a.x + b.x);
        sWt[(n4 * 4 + 1) * 136 + k] = (__bf16)(a.y + b.y);
        sWt[(n4 * 4 + 2) * 136 + k] = (__bf16)(a.z + b.z);
        sWt[(n4 * 4 + 3) * 136 + k] = (__bf16)(a.w + b.w);
    }
    __syncthreads();
    if (!valid) return;

    // ---- main loop: pure ds_read_b128 + MFMA ----
    f32x4 acc[2][8] = {};   // 2 row-groups (16 rows) x 8 col-tiles
    #pragma unroll
    for (int kc = 0; kc < 4; ++kc) {
        const int ko = kc * 32 + quad * 8;
        #pragma unroll
        for (int ct = 0; ct < 8; ++ct) {
            // A-fragment: A[m = out_col = ct*16 + l16][k]
            bf16x8 wa = *(const bf16x8*)&sWt[(ct * 16 + l16) * 136 + ko];
            acc[0][ct] = __builtin_amdgcn_mfma_f32_16x16x32_bf16(wa, xb[0][kc], acc[0][ct], 0, 0, 0);
            acc[1][ct] = __builtin_amdgcn_mfma_f32_16x16x32_bf16(wa, xb[1][kc], acc[1][ct], 0, 0, 0);
        }
    }

    // ---- epilogue: D[m=out_col][n=x_row]; cols quad*4+reg contiguous ----
    #pragma unroll
    for (int g = 0; g < 2; ++g) {
        float* orow = out + (rowbase + g * 16 + l16) * 128 + quad * 4;
        #pragma unroll
        for (int ct = 0; ct < 8; ++ct) {
            f32x4 bv = *(const f32x4*)(bias_g + ct * 16 + quad * 4);
            f32x4 v = acc[g][ct] + bv;
            __builtin_nontemporal_store(v, (f32x4*)(orow + ct * 16));
        }
    }
}

extern "C" void kernel_launch(void* const* d_in, const int* in_sizes, int n_in,
                              void* d_out, int out_size, void* d_ws, size_t ws_size,
                              hipStream_t stream) {
    const float* x  = (const float*)d_in[0];
    // d_in[1] = edge_index (int64) -- dead code in the reference, never read.
    const float* Wc = (const float*)d_in[2];
    const float* Wn = (const float*)d_in[3];
    const float* b  = (const float*)d_in[4];
    float* out = (float*)d_out;

    const int nblocks = (NROWS + 127) / 128;      // 782
    fout_fused<<<nblocks, 256, 0, stream>>>(x, Wc, Wn, b, out);
}

// Round 5
// 117.333 us; speedup vs baseline: 1.0813x; 1.0813x over previous
//
#include <hip/hip_runtime.h>
#include <hip/hip_bf16.h>

// out = x @ (Wc + Wn) + b   -- gamma/segment ops in the reference are dead code.
// x: [100000,128] f32, Wc/Wn: [128,128] f32, b: [128] f32, out: [100000,128] f32.
//
// Two kernels (R4 post-mortem: in-block transpose = 32-way ds_write_b16 bank
// conflicts, 6.4M conflict cycles + 4x W staging traffic -> 44us. Split puts
// the transpose in a tiny prep kernel so gemm staging is contiguous b128):
//   1. prep_wt: wt[n][k] = bf16(Wc[k][n]+Wn[k][n])  (coalesced read, linear write)
//   2. gemm: x prefetch first (HBM-critical stream in flight early), then
//      conflict-free b128 LDS staging of wt, pure ds_read_b128+MFMA loop.
// MFMA operands: A = W^T fragment, B = x fragment (identical input lane maps)
// -> D[m=out_col][n=x_row] gives 4 contiguous out columns/lane -> float4 stores.

#define NROWS 100000

typedef __attribute__((ext_vector_type(8))) __bf16 bf16x8;
typedef __attribute__((ext_vector_type(4))) float f32x4;

__device__ __forceinline__ bf16x8 pack8(const float4 lo, const float4 hi) {
    bf16x8 r;  // gfx950: v_cvt_pk_bf16_f32 (RNE)
    r[0] = (__bf16)lo.x; r[1] = (__bf16)lo.y; r[2] = (__bf16)lo.z; r[3] = (__bf16)lo.w;
    r[4] = (__bf16)hi.x; r[5] = (__bf16)hi.y; r[6] = (__bf16)hi.z; r[7] = (__bf16)hi.w;
    return r;
}

// Build Wt[n][k] = bf16(Wc[k][n] + Wn[k][n]) in workspace. Consecutive threads
// share k, vary n -> global reads coalesced; writes are transposed-scatter but
// it's only 16K elements (~2us dispatch).
__global__ void prep_wt(const float* __restrict__ Wc, const float* __restrict__ Wn,
                        __bf16* __restrict__ wt) {
    int i = blockIdx.x * 256 + threadIdx.x;   // wt laid out [n][k], i = n*128+k
    int n = i >> 7, k = i & 127;
    wt[i] = (__bf16)(Wc[k * 128 + n] + Wn[k * 128 + n]);
}

// 128 rows per block, 4 waves x 32 rows, full N=128 / K=128 per block.
__global__ __launch_bounds__(256) void gemm_bias(
    const float* __restrict__ x, const __bf16* __restrict__ wt,
    const float* __restrict__ bias_g, float* __restrict__ out) {

    // 136-short row stride: rows 16B-aligned (272B); fragment reads land
    // lane l16 on banks {4*l16..4*l16+3} mod 32 -> 2-way aliasing = free (m136).
    __shared__ __align__(16) __bf16 sWt[128 * 136];

    const int tid  = threadIdx.x;
    const int wave = tid >> 6;
    const int lane = tid & 63;
    const int quad = lane >> 4;
    const int l16  = lane & 15;

    const long rowbase = (long)blockIdx.x * 128 + wave * 32;
    const bool valid = rowbase < NROWS;   // 100000 % 32 == 0: whole-wave granularity

    // ---- x prefetch FIRST: all fragments, converted to bf16 (32 VGPRs) ----
    // B[k = quad*8 + j][n = lane&15] -> rows (rowbase+l16) and (+16)
    bf16x8 xb[2][4];
    if (valid) {
        const float* xr0 = x + (rowbase + l16) * 128;
        const float* xr1 = xr0 + 16 * 128;
        #pragma unroll
        for (int kc = 0; kc < 4; ++kc) {
            const int ko = kc * 32 + quad * 8;
            xb[0][kc] = pack8(*(const float4*)(xr0 + ko), *(const float4*)(xr0 + ko + 4));
            xb[1][kc] = pack8(*(const float4*)(xr1 + ko), *(const float4*)(xr1 + ko + 4));
        }
    }

    // ---- W staging: contiguous b128 reads of pre-transposed wt -> b128 LDS
    // writes. Lanes 0..15 cover one 272B row contiguously -> conflict-free.
    #pragma unroll
    for (int it = 0; it < 8; ++it) {
        int idx8 = it * 256 + tid;           // 16B chunk id, 16 chunks per row
        int n = idx8 >> 4;
        int k = (idx8 & 15) << 3;
        *(bf16x8*)&sWt[n * 136 + k] = *(const bf16x8*)(wt + (idx8 << 3));
    }
    __syncthreads();
    if (!valid) return;

    // bias for cols ct*16 + quad*4 .. +3 (L1-hot broadcast)
    f32x4 bv[8];
    #pragma unroll
    for (int ct = 0; ct < 8; ++ct)
        bv[ct] = *(const f32x4*)(bias_g + ct * 16 + quad * 4);

    // ---- main loop: pure ds_read_b128 + MFMA ----
    f32x4 acc[2][8] = {};   // 2 row-groups (16 rows) x 8 col-tiles
    #pragma unroll
    for (int kc = 0; kc < 4; ++kc) {
        const int ko = kc * 32 + quad * 8;
        #pragma unroll
        for (int ct = 0; ct < 8; ++ct) {
            // A-fragment: A[m = out_col = ct*16 + l16][k]
            bf16x8 wa = *(const bf16x8*)&sWt[(ct * 16 + l16) * 136 + ko];
            acc[0][ct] = __builtin_amdgcn_mfma_f32_16x16x32_bf16(wa, xb[0][kc], acc[0][ct], 0, 0, 0);
            acc[1][ct] = __builtin_amdgcn_mfma_f32_16x16x32_bf16(wa, xb[1][kc], acc[1][ct], 0, 0, 0);
        }
    }

    // ---- epilogue: D[m=out_col][n=x_row]; cols quad*4+reg contiguous ----
    #pragma unroll
    for (int g = 0; g < 2; ++g) {
        float* orow = out + (rowbase + g * 16 + l16) * 128 + quad * 4;
        #pragma unroll
        for (int ct = 0; ct < 8; ++ct) {
            f32x4 v = acc[g][ct] + bv[ct];
            __builtin_nontemporal_store(v, (f32x4*)(orow + ct * 16));
        }
    }
}

extern "C" void kernel_launch(void* const* d_in, const int* in_sizes, int n_in,
                              void* d_out, int out_size, void* d_ws, size_t ws_size,
                              hipStream_t stream) {
    const float* x  = (const float*)d_in[0];
    // d_in[1] = edge_index (int64) -- dead code in the reference, never read.
    const float* Wc = (const float*)d_in[2];
    const float* Wn = (const float*)d_in[3];
    const float* b  = (const float*)d_in[4];
    __bf16* wt = (__bf16*)d_ws;   // 32 KB scratch
    float* out = (float*)d_out;

    prep_wt<<<64, 256, 0, stream>>>(Wc, Wn, wt);
    const int nblocks = (NROWS + 127) / 128;      // 782
    gemm_bias<<<nblocks, 256, 0, stream>>>(x, wt, b, out);
}